// Round 3
// baseline (259.311 us; speedup 1.0000x reference)
//
#include <hip/hip_runtime.h>
#include <math.h>

typedef __attribute__((ext_vector_type(8))) short short8;
typedef __attribute__((ext_vector_type(4))) float f32x4;

__device__ __forceinline__ unsigned f2bf(float f) {
  unsigned u = __float_as_uint(f);
  return (u + 0x7FFFu + ((u >> 16) & 1u)) >> 16;
}
__device__ __forceinline__ unsigned pk2(float lo, float hi) {
  return f2bf(lo) | (f2bf(hi) << 16);
}

// ---------------- workspace layout (float offsets) ----------------
#define WS_X1    0                    // 16384*200
#define WS_W2P   3328000              // w2pre: 128*48*320 bf16 shorts
#define WS_AS    4966400              // 1024
#define WS_AD    4967424              // 1024
#define WS_WEFB  4968464              // weffB: 48*32 bf16
#define WS_S1    4969664              // 40
#define WS_SH1   4969704              // 40
#define WS_S2    4969744              // 40
#define WS_SH2   4969784              // 40
#define WS_H     4970496              // (unused now)
#define WS_P     5232640              // (unused now; region reused by Y3P)
#define WS_HT    5494784              // hT bf16: 256*1024 ushorts
#define WS_Y3P   WS_P                 // 16*64*1400 fp32 (overlays P region)
#define WS_Y5    8400768              // 16*1400
#define WS_ZP    8455936              // 7*16*1024
#define WS_Z2P   8570624              // 8*16*1024
#define WS_WPT   8701696              // 256*224 bf16 -> end 8730368
#define WS_Y2    8730368              // y2 bf16: 573440*40 ushorts = 5734400 floats
// end ~14.46M floats = 57.9 MB (ws is >=256 MB per harness poison-fill)

// ---------------- k0: params + wpadT + weffB + w2pre ----------------
__global__ __launch_bounds__(256) void k0_prep(const float* __restrict__ gat_W,
                        const float* __restrict__ conv1_w, const float* __restrict__ conv1_b,
                        const float* __restrict__ bn1_g, const float* __restrict__ bn1_b,
                        const float* __restrict__ bn1_m, const float* __restrict__ bn1_v,
                        const float* __restrict__ conv2_b,
                        const float* __restrict__ bn2_g, const float* __restrict__ bn2_b,
                        const float* __restrict__ bn2_m, const float* __restrict__ bn2_v,
                        const float* __restrict__ w2,
                        float* __restrict__ ws) {
  int bx = blockIdx.x, t = threadIdx.x;
  if (bx < 224) {
    unsigned short* wpt = (unsigned short*)(ws + WS_WPT);
    int idx = bx * 256 + t;
    int n = idx / 224, k = idx % 224;
    float v = (n < 200 && k < 200) ? gat_W[k * 200 + n] : 0.f;
    wpt[idx] = (unsigned short)f2bf(v);
    return;
  }
  if (bx == 224) {
    if (t < 48) {
      unsigned short* wb = (unsigned short*)(ws + WS_WEFB);
      float wv[30];
      if (t < 40) {
        for (int j = 0; j < 30; ++j) {
          float s = 0.f;
          for (int tt = 0; tt < 5; ++tt) {
            int k = j - tt;
            if (k >= 0 && k < 26) s += conv1_w[t * 26 + k];
          }
          wv[j] = s * 0.2f;
        }
      }
      for (int k = 0; k < 32; ++k)
        wb[t * 32 + k] = (unsigned short)f2bf((t < 40 && k < 30) ? wv[k] : 0.f);
    }
    if (t < 40) {
      float s1 = bn1_g[t] * rsqrtf(bn1_v[t] + 1e-5f);
      ws[WS_S1 + t] = s1;
      ws[WS_SH1 + t] = bn1_b[t] + (conv1_b[t] - bn1_m[t]) * s1;
      float s2 = bn2_g[t] * rsqrtf(bn2_v[t] + 1e-5f);
      ws[WS_S2 + t] = s2;
      ws[WS_SH2 + t] = bn2_b[t] + (conv2_b[t] - bn2_m[t]) * s2;
    }
    return;
  }
  __shared__ unsigned short lds[2560];
  int q = bx - 225;
  int c8 = q / 6, o0 = (q % 6) * 8;
  unsigned short* w2p = (unsigned short*)(ws + WS_W2P);
#pragma unroll
  for (int i = 0; i < 10; ++i) {
    int e = i * 256 + t;
    int o = e / 320, rr = e % 320;
    int c = rr / 8, nl = rr % 8;
    int oa = o0 + o;
    float v = (oa < 40) ? w2[(oa * 40 + c) * 1024 + c8 * 8 + nl] : 0.f;
    lds[o * 320 + nl * 40 + c] = (unsigned short)f2bf(v);
  }
  __syncthreads();
  uint4* src = (uint4*)lds;
  uint4* dst = (uint4*)(w2p + (c8 * 48 + o0) * 320);
  for (int i = t; i < 320; i += 256) dst[i] = src[i];
}

// ---------------- k1 v2: MFMA GEMM + fused attention scores ----------------
// Changes vs v1: (a) B fragments loaded DIRECT from global wpt (112 KB, L2/L1-hot
// across all 256 blocks) -> Bt LDS array and ALL c-loop barriers deleted (one
// __syncthreads total, LDS 59->30 KB). (b) blocks<16 accumulate per-row
// s=h.att_src / d=h.att_dst partials in registers across c-chunks; one 16-lane
// shfl_xor butterfly at the end writes as_/ad_ -> k1b kernel deleted, h f32
// array deleted (kAttn consumes hT bf16 only).
__global__ __launch_bounds__(256) void k1_mfma(const float* __restrict__ x,
                                               const unsigned short* __restrict__ wpt,
                                               const float* __restrict__ att_src,
                                               const float* __restrict__ att_dst,
                                               const float* __restrict__ gat_b,
                                               unsigned short* __restrict__ hT,
                                               float* __restrict__ x1,
                                               float* __restrict__ as_,
                                               float* __restrict__ ad_) {
  __shared__ unsigned short As[64 * 232];
  int t = threadIdx.x;
  int wave = t >> 6, lane = t & 63;
  int m16 = lane & 15, quad = lane >> 4;
  int row0 = blockIdx.x * 64;
  {
    int m = t >> 2, kq = (t & 3) * 8;
    const float* xr = x + (row0 + m) * 200;
#pragma unroll
    for (int s = 0; s < 7; ++s) {
      int kg = s * 32 + kq;
      uint4 pv;
      if (kg + 8 <= 200) {
        float4 a = *(const float4*)(xr + kg);
        float4 b = *(const float4*)(xr + kg + 4);
        pv.x = pk2(a.x, a.y); pv.y = pk2(a.z, a.w);
        pv.z = pk2(b.x, b.y); pv.w = pk2(b.z, b.w);
      } else {
        float e[8];
#pragma unroll
        for (int q = 0; q < 8; ++q) e[q] = (kg + q < 200) ? xr[kg + q] : 0.f;
        pv.x = pk2(e[0], e[1]); pv.y = pk2(e[2], e[3]);
        pv.z = pk2(e[4], e[5]); pv.w = pk2(e[6], e[7]);
      }
      *(uint4*)&As[m * 232 + kg] = pv;
    }
  }
  __syncthreads();
  bool first = blockIdx.x < 16;
  float sreg[4] = {0.f, 0.f, 0.f, 0.f};
  float dreg[4] = {0.f, 0.f, 0.f, 0.f};
  for (int c = 0; c < 4; ++c) {
    int n0 = c * 64;
    f32x4 acc[4];
#pragma unroll
    for (int nt = 0; nt < 4; ++nt) acc[nt] = (f32x4){0.f, 0.f, 0.f, 0.f};
#pragma unroll
    for (int s = 0; s < 7; ++s) {
      short8 af = *(const short8*)&As[(wave * 16 + m16) * 232 + s * 32 + quad * 8];
      int kb = s * 32 + quad * 8;
#pragma unroll
      for (int nt = 0; nt < 4; ++nt) {
        short8 bf = *(const short8*)&wpt[(n0 + nt * 16 + m16) * 224 + kb];
        acc[nt] = __builtin_amdgcn_mfma_f32_16x16x32_bf16(af, bf, acc[nt], 0, 0, 0);
      }
    }
    if (first) {
#pragma unroll
      for (int nt = 0; nt < 4; ++nt) {
        int col = n0 + nt * 16 + m16;
        float sa = (col < 200) ? att_src[col] : 0.f;
        float da = (col < 200) ? att_dst[col] : 0.f;
#pragma unroll
        for (int r = 0; r < 4; ++r) {
          int row = row0 + wave * 16 + quad * 4 + r;
          float v = acc[nt][r];
          hT[col * 1024 + row] = (unsigned short)f2bf(v);
          sreg[r] += v * sa;
          dreg[r] += v * da;
        }
      }
    } else {
#pragma unroll
      for (int nt = 0; nt < 4; ++nt) {
        int col = n0 + nt * 16 + m16;
        if (col < 200) {
          float gb = gat_b[col];
#pragma unroll
          for (int r = 0; r < 4; ++r) {
            int row = row0 + wave * 16 + quad * 4 + r;
            x1[row * 200 + col] = x[row * 200 + col] + acc[nt][r] + gb;
          }
        }
      }
    }
  }
  if (first) {
#pragma unroll
    for (int r = 0; r < 4; ++r) {
#pragma unroll
      for (int off = 1; off < 16; off <<= 1) {
        sreg[r] += __shfl_xor(sreg[r], off);
        dreg[r] += __shfl_xor(dreg[r], off);
      }
    }
    if (m16 == 0) {
#pragma unroll
      for (int r = 0; r < 4; ++r) {
        int row = row0 + wave * 16 + quad * 4 + r;
        as_[row] = sreg[r];
        ad_[row] = dreg[r];
      }
    }
  }
}

// ---------------- kAttn v4: fused softmax (unnormalized-P, scale-after-MFMA) ----
// grid (64 i-tiles, 4 f-tiles), block 256. The MFMA is linear, so P need not be
// normalized before the matmul: each lane computes its OWN unnormalized bf16 P
// fragments in-register (exp(leaky(as+ad)-M), M from a block max over as_[1024]);
// row sums reduced via LDS; epilogue scales by inv[row]. kP kernel and the 2 MB
// P round-trip are gone. LDS 21.5 KB.
__global__ __launch_bounds__(256) void kAttn(const float* __restrict__ as_,
                                             const float* __restrict__ ad_,
                                             const unsigned short* __restrict__ hT,
                                             const float* __restrict__ x,
                                             const float* __restrict__ gat_b,
                                             float* __restrict__ x1) {
  __shared__ float asl[1024];
  __shared__ float rs[256];
  __shared__ float invl[16];
  __shared__ float red[4][1024];
  int t = threadIdx.x;
  int wave = t >> 6, lane = t & 63;
  int l15 = lane & 15, quad = lane >> 4;
  int i0 = blockIdx.x * 16, f0 = blockIdx.y * 64;
  // stage as_ into LDS + block-wide max
  float4 av = ((const float4*)as_)[t];
  ((float4*)asl)[t] = av;
  float m0 = fmaxf(fmaxf(av.x, av.y), fmaxf(av.z, av.w));
#pragma unroll
  for (int off = 32; off > 0; off >>= 1) m0 = fmaxf(m0, __shfl_xor(m0, off));
  if (lane == 0) rs[wave] = m0;
  __syncthreads();
  float maxs = fmaxf(fmaxf(rs[0], rs[1]), fmaxf(rs[2], rs[3]));
  __syncthreads();  // rs about to be reused
  // per-lane unnormalized P fragments for row i0+l15, cols wave*256+ks*32+quad*8..+8
  float ad = ad_[i0 + l15];
  float mv = maxs + ad;
  float M = mv >= 0.f ? mv : 0.2f * mv;
  short8 af[8];
  float psum = 0.f;
#pragma unroll
  for (int ks = 0; ks < 8; ++ks) {
    int j0 = wave * 256 + ks * 32 + quad * 8;
    float p[8];
#pragma unroll
    for (int m = 0; m < 8; ++m) {
      float v = asl[j0 + m] + ad;
      float l = v >= 0.f ? v : 0.2f * v;
      p[m] = __expf(l - M);
      psum += p[m];
    }
    ((uint*)&af[ks])[0] = pk2(p[0], p[1]);
    ((uint*)&af[ks])[1] = pk2(p[2], p[3]);
    ((uint*)&af[ks])[2] = pk2(p[4], p[5]);
    ((uint*)&af[ks])[3] = pk2(p[6], p[7]);
  }
  rs[t] = psum;  // t = wave*64 + quad*16 + l15
  __syncthreads();
  if (t < 16) {
    float s = 0.f;
#pragma unroll
    for (int g = 0; g < 16; ++g) s += rs[g * 16 + t];
    invl[t] = 1.f / s;
  }
  f32x4 acc[4];
#pragma unroll
  for (int nt = 0; nt < 4; ++nt) acc[nt] = (f32x4){0.f, 0.f, 0.f, 0.f};
#pragma unroll
  for (int ks = 0; ks < 8; ++ks) {
    int koff = wave * 256 + ks * 32 + quad * 8;
#pragma unroll
    for (int nt = 0; nt < 4; ++nt) {
      short8 bf = *(const short8*)&hT[(f0 + nt * 16 + l15) * 1024 + koff];
      acc[nt] = __builtin_amdgcn_mfma_f32_16x16x32_bf16(af[ks], bf, acc[nt], 0, 0, 0);
    }
  }
#pragma unroll
  for (int nt = 0; nt < 4; ++nt)
#pragma unroll
    for (int r = 0; r < 4; ++r)
      red[wave][(quad * 4 + r) * 64 + nt * 16 + l15] = acc[nt][r];
  __syncthreads();
#pragma unroll
  for (int e = 0; e < 4; ++e) {
    int idx = t * 4 + e;
    int row = idx >> 6, col = idx & 63;
    int cg = f0 + col;
    if (cg < 200) {
      float s = (red[0][idx] + red[1][idx] + red[2][idx] + red[3][idx]) * invl[row];
      int rg = i0 + row;
      x1[rg * 200 + cg] = x[rg * 200 + cg] + s + gat_b[cg];
    }
  }
}

// ---------------- k3a: conv1+bn1+elu -> y2 bf16. ZERO LDS, ZERO barriers. ----------
__global__ __launch_bounds__(256) void k3a_conv1(const float* __restrict__ x1,
                                                 const unsigned short* __restrict__ weffB,
                                                 const float* __restrict__ ws,
                                                 unsigned short* __restrict__ y2) {
  int t = threadIdx.x;
  int wave = t >> 6, lane = t & 63;
  int l15 = lane & 15, quad = lane >> 4;
  int tile = blockIdx.x * 4 + wave;   // 35840 tiles exactly
  int row = tile * 16 + l15;          // < 573440 exactly
  int nn = row / 35;                  // (b,n) combined row of x1
  int p = row - nn * 35;
  short8 bw[3];
#pragma unroll
  for (int nt = 0; nt < 3; ++nt)
    bw[nt] = *(const short8*)&weffB[(nt * 16 + l15) * 32 + quad * 8];
  const float* xr = x1 + nn * 200 + p * 5;
  int k0 = quad * 8;
  float e[8];
#pragma unroll
  for (int j = 0; j < 8; ++j) {
    int k = k0 + j;
    e[j] = (k < 30) ? xr[k] : 0.f;
  }
  short8 xf;
  ((uint*)&xf)[0] = pk2(e[0], e[1]);
  ((uint*)&xf)[1] = pk2(e[2], e[3]);
  ((uint*)&xf)[2] = pk2(e[4], e[5]);
  ((uint*)&xf)[3] = pk2(e[6], e[7]);
  unsigned short* yrow = y2 + row * 40;
#pragma unroll
  for (int nt = 0; nt < 3; ++nt) {
    f32x4 z = {0.f, 0.f, 0.f, 0.f};
    f32x4 c4 = __builtin_amdgcn_mfma_f32_16x16x32_bf16(bw[nt], xf, z, 0, 0, 0);
    int c0 = nt * 16 + quad * 4;
    if (c0 < 40) {
      float4 s1q = *(const float4*)(ws + WS_S1 + c0);
      float4 sh1q = *(const float4*)(ws + WS_SH1 + c0);
      float v0 = c4[0] * s1q.x + sh1q.x;
      float v1 = c4[1] * s1q.y + sh1q.y;
      float v2 = c4[2] * s1q.z + sh1q.z;
      float v3 = c4[3] * s1q.w + sh1q.w;
      v0 = v0 > 0.f ? v0 : __expf(v0) - 1.f;
      v1 = v1 > 0.f ? v1 : __expf(v1) - 1.f;
      v2 = v2 > 0.f ? v2 : __expf(v2) - 1.f;
      v3 = v3 > 0.f ? v3 : __expf(v3) - 1.f;
      uint2 pv;
      pv.x = pk2(v0, v1);
      pv.y = pk2(v2, v3);
      *(uint2*)&yrow[c0] = pv;
    }
  }
}

// ---------------- k3b: conv2 as split-K GEMM, partials -> y3p ----------------
__global__ __launch_bounds__(256) void k3b_conv2(const unsigned short* __restrict__ y2,
                                                 const unsigned short* __restrict__ w2pre,
                                                 float* __restrict__ y3p) {
  __shared__ float red[2][48 * 49];
  int t = threadIdx.x;
  int wave = t >> 6, lane = t & 63;
  int l15 = lane & 15, quad = lane >> 4;
  int b = blockIdx.x, kc = blockIdx.y;  // (16, 64)
  const unsigned short* Ab = y2 + (b * 1024 + kc * 16) * 1400;
  int pA[3];
#pragma unroll
  for (int mt = 0; mt < 3; ++mt) {
    int p = mt * 16 + l15;
    pA[mt] = p > 34 ? 34 : p;
  }
  f32x4 acc[3][3];
#pragma unroll
  for (int mt = 0; mt < 3; ++mt)
#pragma unroll
    for (int nt = 0; nt < 3; ++nt) acc[mt][nt] = (f32x4){0.f, 0.f, 0.f, 0.f};
#pragma unroll
  for (int j = 0; j < 5; ++j) {
    int klocal = wave * 160 + j * 32 + quad * 8;
    int noff = klocal / 40;
    int c = klocal - noff * 40;
    const unsigned short* Ak = Ab + noff * 1400 + c;
    short8 a[3];
#pragma unroll
    for (int mt = 0; mt < 3; ++mt)
      a[mt] = *(const short8*)&Ak[pA[mt] * 40];
    int kg = kc * 640 + klocal;
    int slab = kg / 320;
    int kl = kg - slab * 320;
    const unsigned short* Bb = w2pre + slab * 48 * 320 + kl;
    short8 bb[3];
#pragma unroll
    for (int nt = 0; nt < 3; ++nt)
      bb[nt] = *(const short8*)&Bb[(nt * 16 + l15) * 320];
#pragma unroll
    for (int mt = 0; mt < 3; ++mt)
#pragma unroll
      for (int nt = 0; nt < 3; ++nt)
        acc[mt][nt] = __builtin_amdgcn_mfma_f32_16x16x32_bf16(a[mt], bb[nt], acc[mt][nt], 0, 0, 0);
  }
  if (wave < 2) {
    float* r = red[wave];
#pragma unroll
    for (int mt = 0; mt < 3; ++mt)
#pragma unroll
      for (int nt = 0; nt < 3; ++nt)
#pragma unroll
        for (int q = 0; q < 4; ++q)
          r[(mt * 16 + quad * 4 + q) * 49 + nt * 16 + l15] = acc[mt][nt][q];
  }
  __syncthreads();
  if (wave >= 2) {
    float* r = red[wave - 2];
#pragma unroll
    for (int mt = 0; mt < 3; ++mt)
#pragma unroll
      for (int nt = 0; nt < 3; ++nt)
#pragma unroll
        for (int q = 0; q < 4; ++q)
          r[(mt * 16 + quad * 4 + q) * 49 + nt * 16 + l15] += acc[mt][nt][q];
  }
  __syncthreads();
  float* dst = y3p + (b * 64 + kc) * 1400;
  for (int idx = t; idx < 1400; idx += 256) {
    int o = idx / 35, p = idx % 35;
    dst[idx] = red[0][p * 49 + o] + red[1][p * 49 + o];
  }
}

// ---------------- k4: reduce 64 partials + bn2 + elu + projc -> y5 ----------------
__global__ __launch_bounds__(256) void k4_fused(const float* __restrict__ y3p,
                                                const float* __restrict__ ws,
                                                const float* __restrict__ projc_w,
                                                const float* __restrict__ projc_b,
                                                float* __restrict__ y5) {
  __shared__ float tls[1400];
  int t = threadIdx.x, b = blockIdx.x;
  for (int idx = t; idx < 1400; idx += 256) {
    float s = 0.f;
#pragma unroll 4
    for (int q = 0; q < 64; ++q) s += y3p[(b * 64 + q) * 1400 + idx];
    int o = idx / 35;
    float v = s * ws[WS_S2 + o] + ws[WS_SH2 + o];
    tls[idx] = v > 0.f ? v : __expf(v) - 1.f;
  }
  __syncthreads();
  for (int idx = t; idx < 1400; idx += 256) {
    int p = idx / 40, e = idx % 40;
    float acc = projc_b[e];
    for (int o = 0; o < 40; ++o) acc += tls[o * 35 + p] * projc_w[e * 40 + o];
    y5[b * 1400 + idx] = acc;
  }
}

// ---------------- k5: split-K FC1 partials ----------------
__global__ __launch_bounds__(256) void k5_fc1(const float* __restrict__ y5,
                                              const float* __restrict__ W1,
                                              float* __restrict__ zp) {
  __shared__ __align__(16) float yls[3200];
  int t = threadIdx.x;
  int nc = blockIdx.x, kc = blockIdx.y;  // (32, 7)
  for (int i = t; i < 800; i += 256) {
    int bb = i / 50, q = i % 50;
    ((float4*)yls)[bb * 50 + q] = *(const float4*)(y5 + bb * 1400 + kc * 200 + q * 4);
  }
  __syncthreads();
  int nl = t & 31, bg = t >> 5;
  int n = nc * 32 + nl;
  float acc0 = 0.f, acc1 = 0.f;
  const float* y0 = yls + (bg * 2) * 200;
  const float* y1 = yls + (bg * 2 + 1) * 200;
  for (int k = 0; k < 200; ++k) {
    float w = W1[(kc * 200 + k) * 1024 + n];
    acc0 += y0[k] * w;
    acc1 += y1[k] * w;
  }
  zp[(kc * 16 + bg * 2) * 1024 + n] = acc0;
  zp[(kc * 16 + bg * 2 + 1) * 1024 + n] = acc1;
}

// ---------------- k6: split-K FC2 partials, gelu(z) on the fly ----------------
__global__ __launch_bounds__(256) void k6_fc2(const float* __restrict__ zp,
                                              const float* __restrict__ b1,
                                              const float* __restrict__ W2,
                                              float* __restrict__ z2p) {
  __shared__ __align__(16) float gls[2048];
  int t = threadIdx.x;
  int nc = blockIdx.x, kc = blockIdx.y;  // (32, 8)
  for (int i = t; i < 2048; i += 256) {
    int bb = i >> 7, kk = i & 127;
    int np = kc * 128 + kk;
    float s = b1[np];
#pragma unroll
    for (int j = 0; j < 7; ++j) s += zp[(j * 16 + bb) * 1024 + np];
    gls[i] = 0.5f * s * (1.f + erff(s * 0.70710678f));
  }
  __syncthreads();
  int nl = t & 31, bg = t >> 5;
  int n = nc * 32 + nl;
  float acc0 = 0.f, acc1 = 0.f;
  const float* g0 = gls + (bg * 2) * 128;
  const float* g1 = gls + (bg * 2 + 1) * 128;
  for (int k = 0; k < 128; ++k) {
    float w = W2[(kc * 128 + k) * 1024 + n];
    acc0 += g0[k] * w;
    acc1 += g1[k] * w;
  }
  z2p[(kc * 16 + bg * 2) * 1024 + n] = acc0;
  z2p[(kc * 16 + bg * 2 + 1) * 1024 + n] = acc1;
}

// ---------------- k7: z recompute + FC2 reduce + residual + LayerNorm ----------------
__global__ __launch_bounds__(256) void k7_ln(const float* __restrict__ zp,
                                             const float* __restrict__ z2p,
                                             const float* __restrict__ b1,
                                             const float* __restrict__ b2,
                                             const float* __restrict__ ln_g,
                                             const float* __restrict__ ln_b,
                                             float* __restrict__ out) {
  __shared__ float r1[256], r2[256];
  int t = threadIdx.x, b = blockIdx.x;
  float4 v = *(const float4*)(b1 + t * 4);
  float4 bb2 = *(const float4*)(b2 + t * 4);
  v.x += bb2.x; v.y += bb2.y; v.z += bb2.z; v.w += bb2.w;
#pragma unroll
  for (int kc = 0; kc < 7; ++kc) {
    float4 p = *(const float4*)(zp + (kc * 16 + b) * 1024 + t * 4);
    v.x += p.x; v.y += p.y; v.z += p.z; v.w += p.w;
  }
#pragma unroll
  for (int kc = 0; kc < 8; ++kc) {
    float4 p = *(const float4*)(z2p + (kc * 16 + b) * 1024 + t * 4);
    v.x += p.x; v.y += p.y; v.z += p.z; v.w += p.w;
  }
  r1[t] = v.x + v.y + v.z + v.w;
  r2[t] = v.x * v.x + v.y * v.y + v.z * v.z + v.w * v.w;
  __syncthreads();
  for (int s = 128; s > 0; s >>= 1) {
    if (t < s) {
      r1[t] += r1[t + s];
      r2[t] += r2[t + s];
    }
    __syncthreads();
  }
  float mu = r1[0] * (1.f / 1024.f);
  float var = r2[0] * (1.f / 1024.f) - mu * mu;
  float rstd = rsqrtf(var + 1e-5f);
  float4 gg = *(const float4*)(ln_g + t * 4);
  float4 bb = *(const float4*)(ln_b + t * 4);
  float4 o;
  o.x = (v.x - mu) * rstd * gg.x + bb.x;
  o.y = (v.y - mu) * rstd * gg.y + bb.y;
  o.z = (v.z - mu) * rstd * gg.z + bb.z;
  o.w = (v.w - mu) * rstd * gg.w + bb.w;
  *(float4*)(out + b * 1024 + t * 4) = o;
}

extern "C" void kernel_launch(void* const* d_in, const int* in_sizes, int n_in,
                              void* d_out, int out_size, void* d_ws, size_t ws_size,
                              hipStream_t stream) {
  (void)in_sizes; (void)n_in; (void)out_size; (void)ws_size;
  const float* x       = (const float*)d_in[0];
  const float* gat_W   = (const float*)d_in[1];
  const float* att_src = (const float*)d_in[2];
  const float* att_dst = (const float*)d_in[3];
  const float* gat_b   = (const float*)d_in[4];
  const float* conv1_w = (const float*)d_in[5];
  const float* conv2_w = (const float*)d_in[11];
  const float* projc_w = (const float*)d_in[17];
  const float* projc_b = (const float*)d_in[18];
  const float* W1      = (const float*)d_in[19];
  const float* b1      = (const float*)d_in[20];
  const float* W2      = (const float*)d_in[21];
  const float* b2      = (const float*)d_in[22];
  const float* ln_g    = (const float*)d_in[23];
  const float* ln_b    = (const float*)d_in[24];
  float* ws  = (float*)d_ws;
  float* out = (float*)d_out;

  hipLaunchKernelGGL(k0_prep, dim3(993), dim3(256), 0, stream, gat_W, conv1_w,
                     (const float*)d_in[6], (const float*)d_in[7], (const float*)d_in[8],
                     (const float*)d_in[9], (const float*)d_in[10], (const float*)d_in[12],
                     (const float*)d_in[13], (const float*)d_in[14], (const float*)d_in[15],
                     (const float*)d_in[16], conv2_w, ws);
  hipLaunchKernelGGL(k1_mfma, dim3(256), dim3(256), 0, stream, x,
                     (const unsigned short*)(ws + WS_WPT), att_src, att_dst, gat_b,
                     (unsigned short*)(ws + WS_HT), ws + WS_X1, ws + WS_AS, ws + WS_AD);
  hipLaunchKernelGGL(kAttn, dim3(64, 4), dim3(256), 0, stream, ws + WS_AS, ws + WS_AD,
                     (const unsigned short*)(ws + WS_HT), x, gat_b, ws + WS_X1);
  hipLaunchKernelGGL(k3a_conv1, dim3(8960), dim3(256), 0, stream, ws + WS_X1,
                     (const unsigned short*)(ws + WS_WEFB), ws,
                     (unsigned short*)(ws + WS_Y2));
  hipLaunchKernelGGL(k3b_conv2, dim3(16, 64), dim3(256), 0, stream,
                     (const unsigned short*)(ws + WS_Y2),
                     (const unsigned short*)(ws + WS_W2P), ws + WS_Y3P);
  hipLaunchKernelGGL(k4_fused, dim3(16), dim3(256), 0, stream, ws + WS_Y3P, ws, projc_w,
                     projc_b, ws + WS_Y5);
  hipLaunchKernelGGL(k5_fc1, dim3(32, 7), dim3(256), 0, stream, ws + WS_Y5, W1, ws + WS_ZP);
  hipLaunchKernelGGL(k6_fc2, dim3(32, 8), dim3(256), 0, stream, ws + WS_ZP, b1, W2,
                     ws + WS_Z2P);
  hipLaunchKernelGGL(k7_ln, dim3(16), dim3(256), 0, stream, ws + WS_ZP, ws + WS_Z2P, b1, b2,
                     ln_g, ln_b, out);
}

// Round 4
// 228.701 us; speedup vs baseline: 1.1338x; 1.1338x over previous
//
#include <hip/hip_runtime.h>
#include <math.h>

typedef __attribute__((ext_vector_type(8))) short short8;
typedef __attribute__((ext_vector_type(4))) float f32x4;

__device__ __forceinline__ unsigned f2bf(float f) {
  unsigned u = __float_as_uint(f);
  return (u + 0x7FFFu + ((u >> 16) & 1u)) >> 16;
}
__device__ __forceinline__ unsigned pk2(float lo, float hi) {
  return f2bf(lo) | (f2bf(hi) << 16);
}

// ---------------- workspace layout (float offsets) ----------------
#define WS_X1    0                    // 16384*200
#define WS_W2P   3328000              // w2pre: 128*48*320 bf16 shorts
#define WS_AS    4966400              // 1024
#define WS_AD    4967424              // 1024
#define WS_WEFB  4968464              // weffB: 48*32 bf16
#define WS_S1    4969664              // 40
#define WS_SH1   4969704              // 40
#define WS_S2    4969744              // 40
#define WS_SH2   4969784              // 40
#define WS_H     4970496              // 1024*256 fp32
#define WS_P     5232640              // P bf16: 1024*1024 ushorts
#define WS_HT    5494784              // hT bf16: 256*1024 ushorts
#define WS_Y3P   WS_P                 // 16*32*1400 fp32 (overlays P/HT; dead by k3)
#define WS_Y5    8400768              // 16*1400
#define WS_ZP    8455936              // 7*16*1024
#define WS_Z2P   8570624              // 8*16*1024
#define WS_WPT   8701696              // 256*224 bf16
// end 8,730,368 floats = 34.9 MB

// ---------------- k0: params + wpadT + weffB + w2pre ----------------
__global__ __launch_bounds__(256) void k0_prep(const float* __restrict__ gat_W,
                        const float* __restrict__ conv1_w, const float* __restrict__ conv1_b,
                        const float* __restrict__ bn1_g, const float* __restrict__ bn1_b,
                        const float* __restrict__ bn1_m, const float* __restrict__ bn1_v,
                        const float* __restrict__ conv2_b,
                        const float* __restrict__ bn2_g, const float* __restrict__ bn2_b,
                        const float* __restrict__ bn2_m, const float* __restrict__ bn2_v,
                        const float* __restrict__ w2,
                        float* __restrict__ ws) {
  int bx = blockIdx.x, t = threadIdx.x;
  if (bx < 224) {
    unsigned short* wpt = (unsigned short*)(ws + WS_WPT);
    int idx = bx * 256 + t;
    int n = idx / 224, k = idx % 224;
    float v = (n < 200 && k < 200) ? gat_W[k * 200 + n] : 0.f;
    wpt[idx] = (unsigned short)f2bf(v);
    return;
  }
  if (bx == 224) {
    if (t < 48) {
      unsigned short* wb = (unsigned short*)(ws + WS_WEFB);
      float wv[30];
      if (t < 40) {
        for (int j = 0; j < 30; ++j) {
          float s = 0.f;
          for (int tt = 0; tt < 5; ++tt) {
            int k = j - tt;
            if (k >= 0 && k < 26) s += conv1_w[t * 26 + k];
          }
          wv[j] = s * 0.2f;
        }
      }
      for (int k = 0; k < 32; ++k)
        wb[t * 32 + k] = (unsigned short)f2bf((t < 40 && k < 30) ? wv[k] : 0.f);
    }
    if (t < 40) {
      float s1 = bn1_g[t] * rsqrtf(bn1_v[t] + 1e-5f);
      ws[WS_S1 + t] = s1;
      ws[WS_SH1 + t] = bn1_b[t] + (conv1_b[t] - bn1_m[t]) * s1;
      float s2 = bn2_g[t] * rsqrtf(bn2_v[t] + 1e-5f);
      ws[WS_S2 + t] = s2;
      ws[WS_SH2 + t] = bn2_b[t] + (conv2_b[t] - bn2_m[t]) * s2;
    }
    return;
  }
  __shared__ unsigned short lds[2560];
  int q = bx - 225;
  int c8 = q / 6, o0 = (q % 6) * 8;
  unsigned short* w2p = (unsigned short*)(ws + WS_W2P);
#pragma unroll
  for (int i = 0; i < 10; ++i) {
    int e = i * 256 + t;
    int o = e / 320, rr = e % 320;
    int c = rr / 8, nl = rr % 8;
    int oa = o0 + o;
    float v = (oa < 40) ? w2[(oa * 40 + c) * 1024 + c8 * 8 + nl] : 0.f;
    lds[o * 320 + nl * 40 + c] = (unsigned short)f2bf(v);
  }
  __syncthreads();
  uint4* src = (uint4*)lds;
  uint4* dst = (uint4*)(w2p + (c8 * 48 + o0) * 320);
  for (int i = t; i < 320; i += 256) dst[i] = src[i];
}

// ---------------- k1: MFMA GEMM, 256 blocks ----------------
__global__ __launch_bounds__(256) void k1_mfma(const float* __restrict__ x,
                                               const unsigned short* __restrict__ wpt,
                                               const float* __restrict__ gat_b,
                                               float* __restrict__ h,
                                               unsigned short* __restrict__ hT,
                                               float* __restrict__ x1) {
  __shared__ unsigned short As[64 * 232];
  __shared__ unsigned short Bt[64 * 232];
  int t = threadIdx.x;
  int wave = t >> 6, lane = t & 63;
  int m16 = lane & 15, quad = lane >> 4;
  int row0 = blockIdx.x * 64;
  {
    int m = t >> 2, kq = (t & 3) * 8;
    const float* xr = x + (row0 + m) * 200;
#pragma unroll
    for (int s = 0; s < 7; ++s) {
      int kg = s * 32 + kq;
      uint4 pv;
      if (kg + 8 <= 200) {
        float4 a = *(const float4*)(xr + kg);
        float4 b = *(const float4*)(xr + kg + 4);
        pv.x = pk2(a.x, a.y); pv.y = pk2(a.z, a.w);
        pv.z = pk2(b.x, b.y); pv.w = pk2(b.z, b.w);
      } else {
        float e[8];
#pragma unroll
        for (int q = 0; q < 8; ++q) e[q] = (kg + q < 200) ? xr[kg + q] : 0.f;
        pv.x = pk2(e[0], e[1]); pv.y = pk2(e[2], e[3]);
        pv.z = pk2(e[4], e[5]); pv.w = pk2(e[6], e[7]);
      }
      *(uint4*)&As[m * 232 + kg] = pv;
    }
  }
  __syncthreads();
  for (int c = 0; c < 4; ++c) {
    int n0 = c * 64;
    for (int i = t; i < 1792; i += 256) {
      int row = i / 28, ch = i % 28;
      *(short8*)&Bt[row * 232 + ch * 8] = *(const short8*)&wpt[(n0 + row) * 224 + ch * 8];
    }
    __syncthreads();
    f32x4 acc[4];
#pragma unroll
    for (int nt = 0; nt < 4; ++nt) acc[nt] = (f32x4){0.f, 0.f, 0.f, 0.f};
#pragma unroll
    for (int s = 0; s < 7; ++s) {
      short8 af = *(const short8*)&As[(wave * 16 + m16) * 232 + s * 32 + quad * 8];
      int kb = s * 32 + quad * 8;
#pragma unroll
      for (int nt = 0; nt < 4; ++nt) {
        short8 bf = *(const short8*)&Bt[(nt * 16 + m16) * 232 + kb];
        acc[nt] = __builtin_amdgcn_mfma_f32_16x16x32_bf16(af, bf, acc[nt], 0, 0, 0);
      }
    }
    if (blockIdx.x < 16) {
#pragma unroll
      for (int nt = 0; nt < 4; ++nt) {
        int col = n0 + nt * 16 + m16;
#pragma unroll
        for (int r = 0; r < 4; ++r) {
          int row = row0 + wave * 16 + quad * 4 + r;
          float v = acc[nt][r];
          h[row * 256 + col] = v;
          hT[col * 1024 + row] = (unsigned short)f2bf(v);
        }
      }
    } else {
#pragma unroll
      for (int nt = 0; nt < 4; ++nt) {
        int col = n0 + nt * 16 + m16;
        if (col < 200) {
          float gb = gat_b[col];
#pragma unroll
          for (int r = 0; r < 4; ++r) {
            int row = row0 + wave * 16 + quad * 4 + r;
            x1[row * 200 + col] = x[row * 200 + col] + acc[nt][r] + gb;
          }
        }
      }
    }
    __syncthreads();
  }
}

// ---------------- k1b: attention scores — wave-per-row ----------------
__global__ __launch_bounds__(256) void k1b_scores(const float* __restrict__ h,
                                                  const float* __restrict__ att_src,
                                                  const float* __restrict__ att_dst,
                                                  float* __restrict__ as_,
                                                  float* __restrict__ ad_) {
  int t = threadIdx.x;
  int wave = t >> 6, lane = t & 63;
  int r = blockIdx.x * 4 + wave;
  float s = 0.f, d = 0.f;
  if (lane < 50) {
    float4 v = *(const float4*)(h + r * 256 + lane * 4);
    float4 a = *(const float4*)(att_src + lane * 4);
    float4 dd = *(const float4*)(att_dst + lane * 4);
    s = v.x * a.x + v.y * a.y + v.z * a.z + v.w * a.w;
    d = v.x * dd.x + v.y * dd.y + v.z * dd.z + v.w * dd.w;
  }
#pragma unroll
  for (int off = 32; off > 0; off >>= 1) {
    s += __shfl_down(s, off);
    d += __shfl_down(d, off);
  }
  if (lane == 0) {
    as_[r] = s;
    ad_[r] = d;
  }
}

// ---------------- kP: normalized softmax P -> bf16 ----------------
__global__ __launch_bounds__(256) void kP(const float* __restrict__ as_,
                                          const float* __restrict__ ad_,
                                          unsigned short* __restrict__ Pb) {
  __shared__ float rb[256];
  int t = threadIdx.x, i = blockIdx.x;
  float a0 = as_[t], a1 = as_[256 + t], a2 = as_[512 + t], a3 = as_[768 + t];
  rb[t] = fmaxf(fmaxf(a0, a1), fmaxf(a2, a3));
  __syncthreads();
  for (int st = 128; st > 0; st >>= 1) {
    if (t < st) rb[t] = fmaxf(rb[t], rb[t + st]);
    __syncthreads();
  }
  float maxs = rb[0];
  __syncthreads();
  float ad = ad_[i];
  float mv = maxs + ad;
  float M = mv >= 0.f ? mv : 0.2f * mv;
  float av[4] = {a0, a1, a2, a3};
  float p[4];
  float s = 0.f;
#pragma unroll
  for (int q = 0; q < 4; ++q) {
    float v = av[q] + ad;
    float l = v >= 0.f ? v : 0.2f * v;
    p[q] = __expf(l - M);
    s += p[q];
  }
  rb[t] = s;
  __syncthreads();
  for (int st = 128; st > 0; st >>= 1) {
    if (t < st) rb[t] += rb[t + st];
    __syncthreads();
  }
  float inv = 1.f / rb[0];
#pragma unroll
  for (int q = 0; q < 4; ++q)
    Pb[i * 1024 + q * 256 + t] = (unsigned short)f2bf(p[q] * inv);
}

// ---------------- kAttn v3: 256 blocks, waves split K, LDS reduce, fused residual ----
// grid (64 i-tiles of 16, 4 f-tiles of 64), block 256 (4 waves).
__global__ __launch_bounds__(256) void kAttn(const unsigned short* __restrict__ Pb,
                                             const unsigned short* __restrict__ hT,
                                             const float* __restrict__ x,
                                             const float* __restrict__ gat_b,
                                             float* __restrict__ x1) {
  __shared__ float red[4][1024];  // 16 KB: per-wave 16x64 C tile
  int t = threadIdx.x;
  int wave = t >> 6, lane = t & 63;
  int l15 = lane & 15, quad = lane >> 4;
  int i0 = blockIdx.x * 16, f0 = blockIdx.y * 64;
  int arow = i0 + l15;
  f32x4 acc[4];
#pragma unroll
  for (int nt = 0; nt < 4; ++nt) acc[nt] = (f32x4){0.f, 0.f, 0.f, 0.f};
#pragma unroll
  for (int ks = 0; ks < 8; ++ks) {
    int koff = wave * 256 + ks * 32 + quad * 8;
    short8 a = *(const short8*)&Pb[arow * 1024 + koff];
#pragma unroll
    for (int nt = 0; nt < 4; ++nt) {
      short8 bf = *(const short8*)&hT[(f0 + nt * 16 + l15) * 1024 + koff];
      acc[nt] = __builtin_amdgcn_mfma_f32_16x16x32_bf16(a, bf, acc[nt], 0, 0, 0);
    }
  }
#pragma unroll
  for (int nt = 0; nt < 4; ++nt)
#pragma unroll
    for (int r = 0; r < 4; ++r)
      red[wave][(quad * 4 + r) * 64 + nt * 16 + l15] = acc[nt][r];
  __syncthreads();
  // 256 threads x 4 elems: reduce 4 waves + residual
#pragma unroll
  for (int e = 0; e < 4; ++e) {
    int idx = t * 4 + e;          // idx in [0,1024)
    int row = idx >> 6, col = idx & 63;
    int cg = f0 + col;
    if (cg < 200) {
      float s = red[0][idx] + red[1][idx] + red[2][idx] + red[3][idx];
      int rg = i0 + row;
      x1[rg * 200 + cg] = x[rg * 200 + cg] + s + gat_b[cg];
    }
  }
}

// ---------------- k3 v14: R0 structure (grid 16x32, 4 its, fused conv1+conv2)
// + the two isolated in-kernel wins from R1's counters:
//  - tA row stride 32 -> 40 shorts (80B = 20 dwords): r*20 mod 32 walks all 8
//    four-bank groups per 16-lane phase; R1 measured conflicts 1.97M -> 1.41M.
//  - conv2 B fragments (w2pre) prefetched into regs at iteration start: L2
//    latency overlaps pack+conv1 instead of stalling conv2 after the t2 barrier.
// Wave 4 computes 2 garbage m-tiles (mi=2,3): reads stay inside smem (clamp 287),
// results masked by m<280. Static mi unroll keeps c4[][] in VGPRs.
__global__ __launch_bounds__(320, 2) void k3_conv(const float* __restrict__ x1,
                                                  const unsigned short* __restrict__ w2pre,
                                                  const unsigned short* __restrict__ weffB,
                                                  const float* __restrict__ ws,
                                                  float* __restrict__ y3p) {
  __shared__ __align__(16) char smem[30016];
  float* xbp = (float*)smem;                              // 8 x 200 fp32
  unsigned short* tA = (unsigned short*)(smem + 6400);    // 288 x 40 bf16 (padded)
  unsigned short* t2 = (unsigned short*)(smem + 6400);    // 36 x 328 bf16 — ALIASES tA
  int t = threadIdx.x;
  int b = blockIdx.x, nc = blockIdx.y;
  int wave = t >> 6, lane = t & 63;
  int l15 = lane & 15, quad = lane >> 4;
  short8 bw[3];
  float s1v[3], sh1v[3];
#pragma unroll
  for (int nt = 0; nt < 3; ++nt) {
    bw[nt] = *(const short8*)&weffB[(nt * 16 + l15) * 32 + quad * 8];
    int c = nt * 16 + l15;
    s1v[nt] = (c < 40) ? ws[WS_S1 + c] : 0.f;
    sh1v[nt] = (c < 40) ? ws[WS_SH1 + c] : 0.f;
  }
  f32x4 acc[3][3];
#pragma unroll
  for (int mt = 0; mt < 3; ++mt)
#pragma unroll
    for (int nt = 0; nt < 3; ++nt) acc[mt][nt] = (f32x4){0.f, 0.f, 0.f, 0.f};
  int mt0 = wave * 4;
  {
    int n0 = nc * 32;
    for (int i = t; i < 400; i += 320) {
      int nn = i / 50, q = i % 50;
      ((float4*)(xbp + nn * 200))[q] = ((const float4*)(x1 + (b * 1024 + n0 + nn) * 200))[q];
    }
  }
  __syncthreads();
  for (int it = 0; it < 4; ++it) {
    int c8 = nc * 4 + it;
    // prefetch conv2 B fragments (global, no LDS dep) — hides L2 latency under pack+conv1
    short8 bb[2][3];
    {
      const unsigned short* bbase = w2pre + c8 * 48 * 320;
#pragma unroll
      for (int ks = 0; ks < 2; ++ks) {
        int koff = wave * 64 + ks * 32 + quad * 8;
#pragma unroll
        for (int nt = 0; nt < 3; ++nt)
          bb[ks][nt] = *(const short8*)&bbase[(nt * 16 + l15) * 320 + koff];
      }
    }
    if (t < 280) {
      int nn = t / 35, p = t % 35;
      const float* xr = xbp + nn * 200 + p * 5;
      uint pv[16];
#pragma unroll
      for (int kk = 0; kk < 15; ++kk) pv[kk] = pk2(xr[kk * 2], xr[kk * 2 + 1]);
      pv[15] = 0u;
      uint4* dst = (uint4*)(tA + t * 40);
      dst[0] = make_uint4(pv[0], pv[1], pv[2], pv[3]);
      dst[1] = make_uint4(pv[4], pv[5], pv[6], pv[7]);
      dst[2] = make_uint4(pv[8], pv[9], pv[10], pv[11]);
      dst[3] = make_uint4(pv[12], pv[13], pv[14], pv[15]);
    } else if (t < 288) {
      uint4 z = make_uint4(0u, 0u, 0u, 0u);
      uint4* dst = (uint4*)(tA + t * 40);
      dst[0] = z; dst[1] = z; dst[2] = z; dst[3] = z;
    }
    __syncthreads();
    // conv1 MFMA -> C in regs (STATIC mi unroll; wave4 mi>=2 garbage, masked later)
    f32x4 c4[4][3];
#pragma unroll
    for (int mi = 0; mi < 4; ++mi) {
      int row = (mt0 + mi) * 16 + l15;
      row = row > 287 ? 287 : row;  // clamp inside padded tA's 288-row span
      short8 a = *(const short8*)&tA[row * 40 + quad * 8];
#pragma unroll
      for (int nt = 0; nt < 3; ++nt) {
        f32x4 z = {0.f, 0.f, 0.f, 0.f};
        c4[mi][nt] = __builtin_amdgcn_mfma_f32_16x16x32_bf16(a, bw[nt], z, 0, 0, 0);
      }
    }
    __syncthreads();  // tA reads done; t2 may overwrite
#pragma unroll
    for (int mi = 0; mi < 4; ++mi) {
      int mt = mt0 + mi;
#pragma unroll
      for (int nt = 0; nt < 3; ++nt) {
        int c = nt * 16 + l15;
        if (c >= 40) continue;
#pragma unroll
        for (int r = 0; r < 4; ++r) {
          int m = mt * 16 + quad * 4 + r;
          if (m < 280) {
            float v = c4[mi][nt][r] * s1v[nt] + sh1v[nt];
            float e = v > 0.f ? v : __expf(v) - 1.f;
            int p = m % 35, nn = m / 35;
            t2[p * 328 + nn * 40 + c] = (unsigned short)f2bf(e);
          }
        }
      }
    }
    __syncthreads();  // t2 ready
    if (it < 3) {
      int n0n = nc * 32 + (it + 1) * 8;
      for (int i = t; i < 400; i += 320) {
        int nn = i / 50, q = i % 50;
        ((float4*)(xbp + nn * 200))[q] = ((const float4*)(x1 + (b * 1024 + n0n + nn) * 200))[q];
      }
    }
#pragma unroll
    for (int ks = 0; ks < 2; ++ks) {
      int koff = wave * 64 + ks * 32 + quad * 8;
      short8 a[3];
#pragma unroll
      for (int mt = 0; mt < 3; ++mt) {
        int row = mt * 16 + l15;
        row = row > 35 ? 35 : row;
        a[mt] = *(const short8*)&t2[row * 328 + koff];
      }
#pragma unroll
      for (int mt = 0; mt < 3; ++mt)
#pragma unroll
        for (int nt = 0; nt < 3; ++nt)
          acc[mt][nt] = __builtin_amdgcn_mfma_f32_16x16x32_bf16(a[mt], bb[ks][nt], acc[mt][nt], 0, 0, 0);
    }
    __syncthreads();
  }
  float* red0 = (float*)smem;
  float* red1 = red0 + 48 * 49;
  if (wave < 2) {
    float* r = wave ? red1 : red0;
#pragma unroll
    for (int mt = 0; mt < 3; ++mt)
#pragma unroll
      for (int nt = 0; nt < 3; ++nt)
#pragma unroll
        for (int q = 0; q < 4; ++q)
          r[(mt * 16 + quad * 4 + q) * 49 + nt * 16 + l15] = acc[mt][nt][q];
  }
  __syncthreads();
  if (wave == 2 || wave == 3) {
    float* r = (wave == 3) ? red1 : red0;
#pragma unroll
    for (int mt = 0; mt < 3; ++mt)
#pragma unroll
      for (int nt = 0; nt < 3; ++nt)
#pragma unroll
        for (int q = 0; q < 4; ++q)
          r[(mt * 16 + quad * 4 + q) * 49 + nt * 16 + l15] += acc[mt][nt][q];
  }
  __syncthreads();
  if (wave == 4) {
#pragma unroll
    for (int mt = 0; mt < 3; ++mt)
#pragma unroll
      for (int nt = 0; nt < 3; ++nt)
#pragma unroll
        for (int q = 0; q < 4; ++q)
          red0[(mt * 16 + quad * 4 + q) * 49 + nt * 16 + l15] += acc[mt][nt][q];
  }
  __syncthreads();
  float* dst = y3p + (b * 32 + nc) * 1400;
  for (int idx = t; idx < 1400; idx += 320) {
    int o = idx / 35, p = idx % 35;
    dst[idx] = red0[p * 49 + o] + red1[p * 49 + o];
  }
}

// ---------------- k4: reduce 32 partials + bn2 + elu + projc -> y5 ----------------
__global__ __launch_bounds__(256) void k4_fused(const float* __restrict__ y3p,
                                                const float* __restrict__ ws,
                                                const float* __restrict__ projc_w,
                                                const float* __restrict__ projc_b,
                                                float* __restrict__ y5) {
  __shared__ float tls[1400];
  int t = threadIdx.x, b = blockIdx.x;
  for (int idx = t; idx < 1400; idx += 256) {
    float s = 0.f;
#pragma unroll 4
    for (int q = 0; q < 32; ++q) s += y3p[(b * 32 + q) * 1400 + idx];
    int o = idx / 35;
    float v = s * ws[WS_S2 + o] + ws[WS_SH2 + o];
    tls[idx] = v > 0.f ? v : __expf(v) - 1.f;
  }
  __syncthreads();
  for (int idx = t; idx < 1400; idx += 256) {
    int p = idx / 40, e = idx % 40;
    float acc = projc_b[e];
    for (int o = 0; o < 40; ++o) acc += tls[o * 35 + p] * projc_w[e * 40 + o];
    y5[b * 1400 + idx] = acc;
  }
}

// ---------------- k5: split-K FC1 partials ----------------
__global__ __launch_bounds__(256) void k5_fc1(const float* __restrict__ y5,
                                              const float* __restrict__ W1,
                                              float* __restrict__ zp) {
  __shared__ __align__(16) float yls[3200];
  int t = threadIdx.x;
  int nc = blockIdx.x, kc = blockIdx.y;  // (32, 7)
  for (int i = t; i < 800; i += 256) {
    int bb = i / 50, q = i % 50;
    ((float4*)yls)[bb * 50 + q] = *(const float4*)(y5 + bb * 1400 + kc * 200 + q * 4);
  }
  __syncthreads();
  int nl = t & 31, bg = t >> 5;
  int n = nc * 32 + nl;
  float acc0 = 0.f, acc1 = 0.f;
  const float* y0 = yls + (bg * 2) * 200;
  const float* y1 = yls + (bg * 2 + 1) * 200;
  for (int k = 0; k < 200; ++k) {
    float w = W1[(kc * 200 + k) * 1024 + n];
    acc0 += y0[k] * w;
    acc1 += y1[k] * w;
  }
  zp[(kc * 16 + bg * 2) * 1024 + n] = acc0;
  zp[(kc * 16 + bg * 2 + 1) * 1024 + n] = acc1;
}

// ---------------- k6: split-K FC2 partials, gelu(z) on the fly ----------------
__global__ __launch_bounds__(256) void k6_fc2(const float* __restrict__ zp,
                                              const float* __restrict__ b1,
                                              const float* __restrict__ W2,
                                              float* __restrict__ z2p) {
  __shared__ __align__(16) float gls[2048];
  int t = threadIdx.x;
  int nc = blockIdx.x, kc = blockIdx.y;  // (32, 8)
  for (int i = t; i < 2048; i += 256) {
    int bb = i >> 7, kk = i & 127;
    int np = kc * 128 + kk;
    float s = b1[np];
#pragma unroll
    for (int j = 0; j < 7; ++j) s += zp[(j * 16 + bb) * 1024 + np];
    gls[i] = 0.5f * s * (1.f + erff(s * 0.70710678f));
  }
  __syncthreads();
  int nl = t & 31, bg = t >> 5;
  int n = nc * 32 + nl;
  float acc0 = 0.f, acc1 = 0.f;
  const float* g0 = gls + (bg * 2) * 128;
  const float* g1 = gls + (bg * 2 + 1) * 128;
  for (int k = 0; k < 128; ++k) {
    float w = W2[(kc * 128 + k) * 1024 + n];
    acc0 += g0[k] * w;
    acc1 += g1[k] * w;
  }
  z2p[(kc * 16 + bg * 2) * 1024 + n] = acc0;
  z2p[(kc * 16 + bg * 2 + 1) * 1024 + n] = acc1;
}

// ---------------- k7: z recompute + FC2 reduce + residual + LayerNorm ----------------
__global__ __launch_bounds__(256) void k7_ln(const float* __restrict__ zp,
                                             const float* __restrict__ z2p,
                                             const float* __restrict__ b1,
                                             const float* __restrict__ b2,
                                             const float* __restrict__ ln_g,
                                             const float* __restrict__ ln_b,
                                             float* __restrict__ out) {
  __shared__ float r1[256], r2[256];
  int t = threadIdx.x, b = blockIdx.x;
  float4 v = *(const float4*)(b1 + t * 4);
  float4 bb2 = *(const float4*)(b2 + t * 4);
  v.x += bb2.x; v.y += bb2.y; v.z += bb2.z; v.w += bb2.w;
#pragma unroll
  for (int kc = 0; kc < 7; ++kc) {
    float4 p = *(const float4*)(zp + (kc * 16 + b) * 1024 + t * 4);
    v.x += p.x; v.y += p.y; v.z += p.z; v.w += p.w;
  }
#pragma unroll
  for (int kc = 0; kc < 8; ++kc) {
    float4 p = *(const float4*)(z2p + (kc * 16 + b) * 1024 + t * 4);
    v.x += p.x; v.y += p.y; v.z += p.z; v.w += p.w;
  }
  r1[t] = v.x + v.y + v.z + v.w;
  r2[t] = v.x * v.x + v.y * v.y + v.z * v.z + v.w * v.w;
  __syncthreads();
  for (int s = 128; s > 0; s >>= 1) {
    if (t < s) {
      r1[t] += r1[t + s];
      r2[t] += r2[t + s];
    }
    __syncthreads();
  }
  float mu = r1[0] * (1.f / 1024.f);
  float var = r2[0] * (1.f / 1024.f) - mu * mu;
  float rstd = rsqrtf(var + 1e-5f);
  float4 gg = *(const float4*)(ln_g + t * 4);
  float4 bb = *(const float4*)(ln_b + t * 4);
  float4 o;
  o.x = (v.x - mu) * rstd * gg.x + bb.x;
  o.y = (v.y - mu) * rstd * gg.y + bb.y;
  o.z = (v.z - mu) * rstd * gg.z + bb.z;
  o.w = (v.w - mu) * rstd * gg.w + bb.w;
  *(float4*)(out + b * 1024 + t * 4) = o;
}

extern "C" void kernel_launch(void* const* d_in, const int* in_sizes, int n_in,
                              void* d_out, int out_size, void* d_ws, size_t ws_size,
                              hipStream_t stream) {
  (void)in_sizes; (void)n_in; (void)out_size; (void)ws_size;
  const float* x       = (const float*)d_in[0];
  const float* gat_W   = (const float*)d_in[1];
  const float* att_src = (const float*)d_in[2];
  const float* att_dst = (const float*)d_in[3];
  const float* gat_b   = (const float*)d_in[4];
  const float* conv1_w = (const float*)d_in[5];
  const float* conv2_w = (const float*)d_in[11];
  const float* projc_w = (const float*)d_in[17];
  const float* projc_b = (const float*)d_in[18];
  const float* W1      = (const float*)d_in[19];
  const float* b1      = (const float*)d_in[20];
  const float* W2      = (const float*)d_in[21];
  const float* b2      = (const float*)d_in[22];
  const float* ln_g    = (const float*)d_in[23];
  const float* ln_b    = (const float*)d_in[24];
  float* ws  = (float*)d_ws;
  float* out = (float*)d_out;

  hipLaunchKernelGGL(k0_prep, dim3(993), dim3(256), 0, stream, gat_W, conv1_w,
                     (const float*)d_in[6], (const float*)d_in[7], (const float*)d_in[8],
                     (const float*)d_in[9], (const float*)d_in[10], (const float*)d_in[12],
                     (const float*)d_in[13], (const float*)d_in[14], (const float*)d_in[15],
                     (const float*)d_in[16], conv2_w, ws);
  hipLaunchKernelGGL(k1_mfma, dim3(256), dim3(256), 0, stream, x,
                     (const unsigned short*)(ws + WS_WPT), gat_b, ws + WS_H,
                     (unsigned short*)(ws + WS_HT), ws + WS_X1);
  hipLaunchKernelGGL(k1b_scores, dim3(256), dim3(256), 0, stream, ws + WS_H, att_src, att_dst,
                     ws + WS_AS, ws + WS_AD);
  hipLaunchKernelGGL(kP, dim3(1024), dim3(256), 0, stream, ws + WS_AS, ws + WS_AD,
                     (unsigned short*)(ws + WS_P));
  hipLaunchKernelGGL(kAttn, dim3(64, 4), dim3(256), 0, stream,
                     (const unsigned short*)(ws + WS_P),
                     (const unsigned short*)(ws + WS_HT), x, gat_b, ws + WS_X1);
  hipLaunchKernelGGL(k3_conv, dim3(16, 32), dim3(320), 0, stream, ws + WS_X1,
                     (const unsigned short*)(ws + WS_W2P),
                     (const unsigned short*)(ws + WS_WEFB), ws, ws + WS_Y3P);
  hipLaunchKernelGGL(k4_fused, dim3(16), dim3(256), 0, stream, ws + WS_Y3P, ws, projc_w,
                     projc_b, ws + WS_Y5);
  hipLaunchKernelGGL(k5_fc1, dim3(32, 7), dim3(256), 0, stream, ws + WS_Y5, W1, ws + WS_ZP);
  hipLaunchKernelGGL(k6_fc2, dim3(32, 8), dim3(256), 0, stream, ws + WS_ZP, b1, W2,
                     ws + WS_Z2P);
  hipLaunchKernelGGL(k7_ln, dim3(16), dim3(256), 0, stream, ws + WS_ZP, ws + WS_Z2P, b1, b2,
                     ln_g, ln_b, out);
}